// Round 8
// baseline (915.235 us; speedup 1.0000x reference)
//
#include <hip/hip_runtime.h>
#include <math.h>

namespace {
constexpr int B_N  = 32;
constexpr int SEQ  = 1024;
constexpr int AG   = 256;
constexpr int D    = 256;
constexpr int NH   = 8;
constexpr float SCALE = 0.0625f;
constexpr float EPS   = 1e-12f;

// workspace byte offsets (total ~88 MB)
constexpr size_t HHI_OFF  = 0;          // ushort(bf16) B*SEQ*D = 16 MB
constexpr size_t HLO_OFF  = 16777216;   // ushort(bf16) B*SEQ*D = 16 MB
constexpr size_t HT_OFF   = 33554432;   // ushort(bf16) B*D*SEQ = 16 MB
constexpr size_t MTHI_OFF = 50331648;   // ushort NH*D*D = 1 MB
constexpr size_t MTLO_OFF = 51380224;   // ushort NH*D*D = 1 MB
constexpr size_t MB_OFF   = 52428800;   // u32 B*AG*SEQ/32 = 1 MB
constexpr size_t WVT_OFF  = 53477376;   // ushort NH*D*D = 1 MB
constexpr size_t Z16_OFF  = 54525952;   // ushort B*NH*AG*D = 33.5 MB
}

typedef __attribute__((ext_vector_type(8))) short short8;
typedef __attribute__((ext_vector_type(4))) float floatx4;
#define MFMA_BF(A,B,C) __builtin_amdgcn_mfma_f32_16x16x32_bf16(A,B,C,0,0,0)

__device__ __forceinline__ unsigned short bf16_rtne(float f) {
    unsigned u = __float_as_uint(f);
    u += 0x7fffu + ((u >> 16) & 1u);
    return (unsigned short)(u >> 16);
}
__device__ __forceinline__ float bf16_tof(unsigned short h) {
    return __uint_as_float(((unsigned)h) << 16);
}
// async global->LDS DMA, 16 B/lane; LDS dst = wave-uniform base + lane*16
__device__ __forceinline__ void async16(void* lds, const void* g) {
    __builtin_amdgcn_global_load_lds(
        (const __attribute__((address_space(1))) unsigned int*)g,
        (__attribute__((address_space(3))) unsigned int*)lds,
        16, 0, 0);
}

// ---------------------------------------------------------------------------
// Encoder: h = lrelu(x)@W_enc^T + b -> h_hi, h_lo (bf16 split, [B,N,D])
// ---------------------------------------------------------------------------
__global__ __launch_bounds__(256) void enc_kernel(
    const float* __restrict__ x, const float* __restrict__ W_enc,
    const float* __restrict__ b_enc,
    ushort* __restrict__ h_hi, ushort* __restrict__ h_lo)
{
    __shared__ float AsT[32][68];
    __shared__ float BsT[32][68];
    const int t  = threadIdx.x;
    const int tx = t & 15, ty = t >> 4;
    const int col0 = blockIdx.x * 64;
    const int row0 = blockIdx.y * 64;

    float acc[4][4];
#pragma unroll
    for (int r = 0; r < 4; ++r)
#pragma unroll
        for (int c = 0; c < 4; ++c) acc[r][c] = 0.f;

    for (int k0 = 0; k0 < 256; k0 += 32) {
        __syncthreads();
#pragma unroll
        for (int ss = 0; ss < 2; ++ss) {
            int flat = t + 256 * ss;
            int rr = flat >> 3, k4 = flat & 7;
            float4 v = *(const float4*)(x + (size_t)(row0 + rr) * 256 + k0 + k4 * 4);
            v.x = v.x > 0.f ? v.x : 0.01f * v.x;
            v.y = v.y > 0.f ? v.y : 0.01f * v.y;
            v.z = v.z > 0.f ? v.z : 0.01f * v.z;
            v.w = v.w > 0.f ? v.w : 0.01f * v.w;
            AsT[k4*4+0][rr] = v.x; AsT[k4*4+1][rr] = v.y;
            AsT[k4*4+2][rr] = v.z; AsT[k4*4+3][rr] = v.w;
            float4 wv = *(const float4*)(W_enc + (size_t)(col0 + rr) * 256 + k0 + k4 * 4);
            BsT[k4*4+0][rr] = wv.x; BsT[k4*4+1][rr] = wv.y;
            BsT[k4*4+2][rr] = wv.z; BsT[k4*4+3][rr] = wv.w;
        }
        __syncthreads();
#pragma unroll 8
        for (int kk = 0; kk < 32; ++kk) {
            float4 a4 = *(const float4*)&AsT[kk][ty * 4];
            float4 b4 = *(const float4*)&BsT[kk][tx * 4];
            const float ar[4] = {a4.x, a4.y, a4.z, a4.w};
            const float bc[4] = {b4.x, b4.y, b4.z, b4.w};
#pragma unroll
            for (int r = 0; r < 4; ++r)
#pragma unroll
                for (int c = 0; c < 4; ++c)
                    acc[r][c] = fmaf(ar[r], bc[c], acc[r][c]);
        }
    }

    float4 bv = *(const float4*)(b_enc + col0 + tx * 4);
    const float bb4[4] = {bv.x, bv.y, bv.z, bv.w};
#pragma unroll
    for (int r = 0; r < 4; ++r) {
        const int row = row0 + ty * 4 + r;
        ushort hi4[4], lo4[4];
#pragma unroll
        for (int c = 0; c < 4; ++c) {
            float v = acc[r][c] + bb4[c];
            hi4[c] = bf16_rtne(v);
            lo4[c] = bf16_rtne(v - bf16_tof(hi4[c]));
        }
        *(ushort4*)(h_hi + (size_t)row * 256 + col0 + tx * 4) =
            make_ushort4(hi4[0], hi4[1], hi4[2], hi4[3]);
        *(ushort4*)(h_lo + (size_t)row * 256 + col0 + tx * 4) =
            make_ushort4(lo4[0], lo4[1], lo4[2], lo4[3]);
    }
}

// ---------------------------------------------------------------------------
// Fused prep: maskbits (vb<1024) | htrans (1024..3071) | wvt (3072..3199) |
// mprep (3200..3327).  Bodies identical to R7's proven kernels; only the
// block-index plumbing changed (saves 3 kernel-launch gaps).
// ---------------------------------------------------------------------------
__global__ __launch_bounds__(256) void prep_fused(
    const float* __restrict__ m, unsigned* __restrict__ mb,
    const ushort* __restrict__ h_hi, ushort* __restrict__ hT,
    const float* __restrict__ WV, ushort* __restrict__ WVt,
    const float* __restrict__ WQ, const float* __restrict__ WK,
    ushort* __restrict__ Mt_hi, ushort* __restrict__ Mt_lo)
{
    __shared__ __align__(16) char plds[17408];
    const int t = threadIdx.x;
    const int v = blockIdx.x;

    if (v < 1024) {
        // ---- maskbits
        const int idx = v * 256 + t;
        const float4* src = (const float4*)(m + (size_t)idx * 32);
        unsigned wbits = 0;
#pragma unroll
        for (int i = 0; i < 8; ++i) {
            float4 vv = src[i];
            wbits |= (vv.x > 0.5f ? 1u : 0u) << (i * 4 + 0);
            wbits |= (vv.y > 0.5f ? 1u : 0u) << (i * 4 + 1);
            wbits |= (vv.z > 0.5f ? 1u : 0u) << (i * 4 + 2);
            wbits |= (vv.w > 0.5f ? 1u : 0u) << (i * 4 + 3);
        }
        mb[idx] = wbits;
    } else if (v < 3072) {
        // ---- htrans: hT[b][d][n] = h_hi[b][n][d] (full coverage, 2 loads)
        ushort (*T)[72] = (ushort(*)[72])plds;   // 9216 B
        const int v1 = v - 1024;
        const int n0 = (v1 & 15) * 64, d0 = ((v1 >> 4) & 3) * 64, b = v1 >> 6;
        {
            const int r = t >> 2, c = (t & 3) * 16;
            const ushort* src = h_hi + ((size_t)(b * 1024 + n0 + r)) * 256 + d0 + c;
            *(short8*)&T[r][c]     = *(const short8*)src;
            *(short8*)&T[r][c + 8] = *(const short8*)(src + 8);
        }
        __syncthreads();
        {
            const int dd = t >> 2, seg = (t & 3) * 16;
            ushort tmp[16];
#pragma unroll
            for (int j = 0; j < 16; ++j) tmp[j] = T[seg + j][dd];
            ushort* dst = hT + ((size_t)(b * 256 + d0 + dd)) * 1024 + n0 + seg;
            *(short8*)dst       = *(short8*)&tmp[0];
            *(short8*)(dst + 8) = *(short8*)&tmp[8];
        }
    } else if (v < 3200) {
        // ---- wvt: WVt[h][e][d] = bf16(WV[h][d][e]); pitch 68 f32 (16B-align)
        float (*T)[68] = (float(*)[68])plds;     // 17408 B
        const int v2 = v - 3072;
        const int d0 = (v2 & 3) * 64, e0 = ((v2 >> 2) & 3) * 64, h = v2 >> 4;
        {
            const int r = t >> 2, c = (t & 3) * 16;
            const float* src = WV + ((size_t)(h * 256 + d0 + r)) * 256 + e0 + c;
#pragma unroll
            for (int j = 0; j < 4; ++j)
                *(float4*)&T[r][c + j * 4] = *(const float4*)(src + j * 4);
        }
        __syncthreads();
        {
            const int ee = t >> 2, seg = (t & 3) * 16;
            ushort tmp[16];
#pragma unroll
            for (int j = 0; j < 16; ++j) tmp[j] = bf16_rtne(T[seg + j][ee]);
            ushort* dst = WVt + ((size_t)(h * 256 + e0 + ee)) * 256 + d0 + seg;
            *(short8*)dst       = *(short8*)&tmp[0];
            *(short8*)(dst + 8) = *(short8*)&tmp[8];
        }
    } else {
        // ---- mprep: Mt_h[d'][d] = (WQ_h @ WK_h^T)[d][d'] -> bf16 hi/lo
        float (*AsT)[68] = (float(*)[68])plds;           // 8704 B
        float (*BsT)[68] = (float(*)[68])(plds + 8704);  // 8704 B
        const int v3 = v - 3200;
        const int tx = t & 15, ty = t >> 4;
        const int col0 = (v3 & 3) * 64;
        const int row0 = ((v3 >> 2) & 3) * 64;
        const int hz   = v3 >> 4;
        const float* A  = WK + (size_t)hz * 256 * 256;
        const float* Bm = WQ + (size_t)hz * 256 * 256;
        ushort* Chi = Mt_hi + (size_t)hz * 256 * 256;
        ushort* Clo = Mt_lo + (size_t)hz * 256 * 256;

        float acc[4][4];
#pragma unroll
        for (int r = 0; r < 4; ++r)
#pragma unroll
            for (int c = 0; c < 4; ++c) acc[r][c] = 0.f;

        for (int k0 = 0; k0 < 256; k0 += 32) {
            __syncthreads();
#pragma unroll
            for (int ss = 0; ss < 2; ++ss) {
                int flat = t + 256 * ss;
                int rr = flat >> 3, k4 = flat & 7;
                float4 vv = *(const float4*)(A + (size_t)(row0 + rr) * 256 + k0 + k4 * 4);
                AsT[k4*4+0][rr] = vv.x; AsT[k4*4+1][rr] = vv.y;
                AsT[k4*4+2][rr] = vv.z; AsT[k4*4+3][rr] = vv.w;
                float4 wv = *(const float4*)(Bm + (size_t)(col0 + rr) * 256 + k0 + k4 * 4);
                BsT[k4*4+0][rr] = wv.x; BsT[k4*4+1][rr] = wv.y;
                BsT[k4*4+2][rr] = wv.z; BsT[k4*4+3][rr] = wv.w;
            }
            __syncthreads();
#pragma unroll 8
            for (int kk = 0; kk < 32; ++kk) {
                float4 a4 = *(const float4*)&AsT[kk][ty * 4];
                float4 b4 = *(const float4*)&BsT[kk][tx * 4];
                const float ar[4] = {a4.x, a4.y, a4.z, a4.w};
                const float bc[4] = {b4.x, b4.y, b4.z, b4.w};
#pragma unroll
                for (int r = 0; r < 4; ++r)
#pragma unroll
                    for (int c = 0; c < 4; ++c)
                        acc[r][c] = fmaf(ar[r], bc[c], acc[r][c]);
            }
        }
#pragma unroll
        for (int r = 0; r < 4; ++r) {
            const int row = row0 + ty * 4 + r;
            ushort hi4[4], lo4[4];
#pragma unroll
            for (int c = 0; c < 4; ++c) {
                float vv = acc[r][c];
                hi4[c] = bf16_rtne(vv);
                lo4[c] = bf16_rtne(vv - bf16_tof(hi4[c]));
            }
            *(ushort4*)(Chi + (size_t)row * 256 + col0 + tx * 4) =
                make_ushort4(hi4[0], hi4[1], hi4[2], hi4[3]);
            *(ushort4*)(Clo + (size_t)row * 256 + col0 + tx * 4) =
                make_ushort4(lo4[0], lo4[1], lo4[2], lo4[3]);
        }
    }
}

// ---------------------------------------------------------------------------
// Attention v6: 512-thread blocks = 2 heads x 4 a-subtiles sharing the
// DMA-staged tiles (head-independent!). 16 waves/CU (2 blocks) vs R7's 8 —
// double the independent work to hide the S->softmax->PV chain and barrier
// drains. Per-wave structure/numerics identical to R7 (proven).
// LDS = hS_hi 16K + hS_lo 16K + hTS 16K + pP[128][40] 10K = 59,392 B.
// ---------------------------------------------------------------------------
__global__ __launch_bounds__(512, 4) void attn_mfma(
    const ushort* __restrict__ h_hi, const ushort* __restrict__ h_lo,
    const ushort* __restrict__ hT,   const ushort* __restrict__ Mt_hi,
    const ushort* __restrict__ Mt_lo, const unsigned* __restrict__ mbits,
    ushort* __restrict__ zout)
{
    __shared__ __align__(16) char lds[59392];
    ushort* hS_hi = (ushort*)lds;             // 16384 B
    ushort* hS_lo = (ushort*)(lds + 16384);   // 16384 B
    ushort* hTS   = (ushort*)(lds + 32768);   // 16384 B
    ushort* pP    = (ushort*)(lds + 49152);   // [128][40] bf16 = 10240 B

    const int t    = threadIdx.x;
    const int wv   = t >> 6;          // 0..7
    const int lane = t & 63;
    const int l15  = lane & 15;
    const int quad = lane >> 4;
    const int f    = blockIdx.x;      // 512 blocks
    const int b    = (f & 7) + 8 * (f >> 7);
    const int mid  = (f >> 3) & 15;
    const int hh   = (mid >> 2) * 2 + (wv >> 2);   // head per wave
    const int a0   = (mid & 3) * 64;
    const int aw   = a0 + (wv & 3) * 16;           // a-subtile per wave

    const ushort* hbh = h_hi + (size_t)b * SEQ * D;
    const ushort* hbl = h_lo + (size_t)b * SEQ * D;
    const ushort* hTb = hT   + (size_t)b * D * SEQ;

    // ---- Phase 0: Q' = ha @ Mt^T (split-bf16 x3), C-layout fp32 tiles
    floatx4 qac[16];
#pragma unroll
    for (int i = 0; i < 16; ++i) qac[i] = (floatx4){0.f, 0.f, 0.f, 0.f};

    for (int kc = 0; kc < 4; ++kc) {
        short8 Ah[2], Al[2];
#pragma unroll
        for (int kt = 0; kt < 2; ++kt) {
            const size_t ao = ((size_t)b * SEQ + aw + l15) * D +
                              kc * 64 + kt * 32 + quad * 8;
            Ah[kt] = *(const short8*)(h_hi + ao);
            Al[kt] = *(const short8*)(h_lo + ao);
        }
#pragma unroll
        for (int nt2 = 0; nt2 < 16; ++nt2) {
#pragma unroll
            for (int kt = 0; kt < 2; ++kt) {
                const size_t mo = ((size_t)hh * D + nt2 * 16 + l15) * D +
                                  kc * 64 + kt * 32 + quad * 8;
                short8 Bh = *(const short8*)(Mt_hi + mo);
                short8 Bl = *(const short8*)(Mt_lo + mo);
                qac[nt2] = MFMA_BF(Ah[kt], Bh, qac[nt2]);
                qac[nt2] = MFMA_BF(Al[kt], Bh, qac[nt2]);
                qac[nt2] = MFMA_BF(Ah[kt], Bl, qac[nt2]);
            }
        }
    }

    // repack Q' C-layout -> bf16 hi/lo A-frags via fp32 scratch overlapping
    // the tile region (rows wv*16.., pitch 68 f32 = 34.8 KB < 48 KB; all
    // pre-loop scratch — the first barrier precedes the first DMA).
    short8 Qhi[8], Qlo[8];
    {
        float* qscr = (float*)lds;
        for (int c = 0; c < 4; ++c) {
#pragma unroll
            for (int j = 0; j < 4; ++j)
#pragma unroll
                for (int r = 0; r < 4; ++r)
                    qscr[(wv * 16 + quad * 4 + r) * 68 + j * 16 + l15] = qac[c * 4 + j][r];
#pragma unroll
            for (int kt = 0; kt < 2; ++kt) {
                const float* pr = &qscr[(wv * 16 + l15) * 68 + kt * 32 + quad * 8];
                float ftmp[8];
                *(float4*)&ftmp[0] = *(const float4*)pr;
                *(float4*)&ftmp[4] = *(const float4*)(pr + 4);
                short8 hi, lo;
#pragma unroll
                for (int e = 0; e < 8; ++e) {
                    unsigned short hb = bf16_rtne(ftmp[e]);
                    hi[e] = (short)hb;
                    lo[e] = (short)bf16_rtne(ftmp[e] - bf16_tof(hb));
                }
                Qhi[c * 2 + kt] = hi;
                Qlo[c * 2 + kt] = lo;
            }
        }
    }

    // ---- Phase 1: flash loop over 32 n-tiles of 32 rows
    floatx4 zac[16];
#pragma unroll
    for (int i = 0; i < 16; ++i) zac[i] = (floatx4){0.f, 0.f, 0.f, 0.f};
    float mx[4] = {-INFINITY, -INFINITY, -INFINITY, -INFINITY};
    float Za[4] = {0.f, 0.f, 0.f, 0.f};
    float Zm[4] = {0.f, 0.f, 0.f, 0.f};

    for (int nt = 0; nt < 32; ++nt) {
        const int n0 = nt * 32;
        __syncthreads();   // prior-tile reads done (also fences Q' scratch)

        // DMA hS_hi / hS_lo: 1024 slots x 16B, spread over 8 waves (2 ea.)
#pragma unroll
        for (int i = 0; i < 2; ++i) {
            const int slot = wv * 128 + i * 64 + lane;
            const int row  = slot >> 5;
            const int p    = slot & 31;
            const int c    = p ^ (row & 7);
            const size_t go = (size_t)(n0 + row) * 256 + c * 8;
            const size_t lo_ = (size_t)(wv * 128 + i * 64) * 8;
            async16(hS_hi + lo_, hbh + go);
            async16(hS_lo + lo_, hbl + go);
        }
        // DMA hTS: row(d) = slot>>2, p = slot&3, c = p ^ ((row>>2)&3)
#pragma unroll
        for (int i = 0; i < 2; ++i) {
            const int slot = wv * 128 + i * 64 + lane;
            const int row  = slot >> 2;
            const int p    = slot & 3;
            const int c    = p ^ ((row >> 2) & 3);
            async16(hTS + (size_t)(wv * 128 + i * 64) * 8,
                    hTb + (size_t)row * 1024 + n0 + c * 8);
        }
        __syncthreads();   // vmcnt drain -> tiles resident

        // S = Q' @ h^T  (split-bf16 x3; swizzled b128 reads)
        floatx4 sac[2];
        sac[0] = (floatx4){0.f, 0.f, 0.f, 0.f};
        sac[1] = (floatx4){0.f, 0.f, 0.f, 0.f};
#pragma unroll
        for (int ks = 0; ks < 8; ++ks) {
            const int cg = ks * 4 + quad;
#pragma unroll
            for (int ntile = 0; ntile < 2; ++ntile) {
                const int row = ntile * 16 + l15;
                const int off = row * 256 + (cg ^ (row & 7)) * 8;
                short8 Bh = *(const short8*)&hS_hi[off];
                short8 Bl = *(const short8*)&hS_lo[off];
                sac[ntile] = MFMA_BF(Qhi[ks], Bh, sac[ntile]);
                sac[ntile] = MFMA_BF(Qlo[ks], Bh, sac[ntile]);
                sac[ntile] = MFMA_BF(Qhi[ks], Bl, sac[ntile]);
            }
        }

        // online masked softmax (row a = a0 + 16*(wv&3) + 4*quad + r)
        float alr[4];
#pragma unroll
        for (int r = 0; r < 4; ++r) {
            const int a = aw + quad * 4 + r;
            const unsigned w0 = mbits[((size_t)b * AG + a) * (SEQ / 32) + nt];
            float l0 = sac[0][r] * SCALE, l1 = sac[1][r] * SCALE;
            float mt = fmaxf(l0, l1);
#pragma unroll
            for (int off = 1; off < 16; off <<= 1) mt = fmaxf(mt, __shfl_xor(mt, off));
            const float mxn = fmaxf(mx[r], mt);
            const float al  = __expf(mx[r] - mxn);
            float e0 = __expf(l0 - mxn), e1 = __expf(l1 - mxn);
            float p0 = ((w0 >> l15) & 1u)        ? e0 : 0.f;
            float p1 = ((w0 >> (16 + l15)) & 1u) ? e1 : 0.f;
            float za = e0 + e1;
            float zm = p0 + p1;
#pragma unroll
            for (int off = 1; off < 16; off <<= 1) {
                za += __shfl_xor(za, off);
                zm += __shfl_xor(zm, off);
            }
            Za[r] = Za[r] * al + za;
            Zm[r] = Zm[r] * al + zm;
            mx[r] = mxn;
            pP[(wv * 16 + quad * 4 + r) * 40 + l15]      = bf16_rtne(p0);
            pP[(wv * 16 + quad * 4 + r) * 40 + 16 + l15] = bf16_rtne(p1);
            alr[r] = al;
        }
#pragma unroll
        for (int dt = 0; dt < 16; ++dt) {
            zac[dt][0] *= alr[0]; zac[dt][1] *= alr[1];
            zac[dt][2] *= alr[2]; zac[dt][3] *= alr[3];
        }

        // z += P @ h : P A-frag (wave-private pP), hTS B-frags (swizzled)
        short8 Pf = *(const short8*)&pP[(wv * 16 + l15) * 40 + quad * 8];
#pragma unroll
        for (int dt = 0; dt < 16; ++dt) {
            const int row = dt * 16 + l15;
            const int p   = quad ^ ((row >> 2) & 3);
            short8 Bf = *(const short8*)&hTS[row * 32 + p * 8];
            zac[dt] = MFMA_BF(Pf, Bf, zac[dt]);
        }
    }

    // epilogue: z_bf16 = z / (Zm + EPS*Za)
#pragma unroll
    for (int r = 0; r < 4; ++r) {
        const int a = aw + quad * 4 + r;
        const float inv = 1.0f / (Zm[r] + EPS * Za[r]);
        ushort* zr = zout + (((size_t)b * NH + hh) * AG + a) * D;
#pragma unroll
        for (int dt = 0; dt < 16; ++dt)
            zr[dt * 16 + l15] = bf16_rtne(zac[dt][r] * inv);
    }
}

// ---------------------------------------------------------------------------
// out[b,a,e] = (1/8) * sum_{h,d} z[b,h,a,d] * WVt[h,e,d]   (bf16 MFMA, K=2048)
// ---------------------------------------------------------------------------
__global__ __launch_bounds__(256) void out_mfma(
    const ushort* __restrict__ z16, const ushort* __restrict__ WVt,
    float* __restrict__ out)
{
    const int t    = threadIdx.x;
    const int wv   = t >> 6;
    const int lane = t & 63;
    const int l15  = lane & 15;
    const int quad = lane >> 4;
    const int e0 = blockIdx.x * 64;
    const int a0 = blockIdx.y * 64;
    const int b  = blockIdx.z;
    const int aw = a0 + wv * 16;

    floatx4 acc[4];
#pragma unroll
    for (int i = 0; i < 4; ++i) acc[i] = (floatx4){0.f, 0.f, 0.f, 0.f};

#pragma unroll 4
    for (int c = 0; c < 64; ++c) {
        const int hh = c >> 3, d0 = (c & 7) * 32;
        short8 Af = *(const short8*)(z16 +
            (((size_t)b * NH + hh) * AG + aw + l15) * D + d0 + quad * 8);
#pragma unroll
        for (int et = 0; et < 4; ++et) {
            short8 Bf = *(const short8*)(WVt +
                ((size_t)hh * D + e0 + et * 16 + l15) * D + d0 + quad * 8);
            acc[et] = MFMA_BF(Af, Bf, acc[et]);
        }
    }
#pragma unroll
    for (int et = 0; et < 4; ++et)
#pragma unroll
        for (int r = 0; r < 4; ++r)
            out[((size_t)b * AG + aw + quad * 4 + r) * D + e0 + et * 16 + l15] =
                acc[et][r] * 0.125f;
}

// ---------------------------------------------------------------------------
extern "C" void kernel_launch(void* const* d_in, const int* in_sizes, int n_in,
                              void* d_out, int out_size, void* d_ws, size_t ws_size,
                              hipStream_t stream)
{
    (void)in_sizes; (void)n_in; (void)out_size; (void)ws_size;
    const float* x     = (const float*)d_in[0];
    const float* m     = (const float*)d_in[1];
    const float* W_enc = (const float*)d_in[2];
    const float* b_enc = (const float*)d_in[3];
    const float* WQ    = (const float*)d_in[4];
    const float* WK    = (const float*)d_in[5];
    const float* WV    = (const float*)d_in[6];
    float* out = (float*)d_out;
    char* ws = (char*)d_ws;

    ushort*   h_hi  = (ushort*)(ws + HHI_OFF);
    ushort*   h_lo  = (ushort*)(ws + HLO_OFF);
    ushort*   hT    = (ushort*)(ws + HT_OFF);
    ushort*   Mt_hi = (ushort*)(ws + MTHI_OFF);
    ushort*   Mt_lo = (ushort*)(ws + MTLO_OFF);
    unsigned* mbits = (unsigned*)(ws + MB_OFF);
    ushort*   WVt   = (ushort*)(ws + WVT_OFF);
    ushort*   z16   = (ushort*)(ws + Z16_OFF);

    enc_kernel<<<dim3(4, 512, 1), dim3(256), 0, stream>>>(
        x, W_enc, b_enc, h_hi, h_lo);
    prep_fused<<<dim3(3328, 1, 1), dim3(256), 0, stream>>>(
        m, mbits, h_hi, hT, WV, WVt, WQ, WK, Mt_hi, Mt_lo);
    attn_mfma<<<dim3(512, 1, 1), dim3(512), 0, stream>>>(
        h_hi, h_lo, hT, Mt_hi, Mt_lo, mbits, z16);
    out_mfma<<<dim3(4, 4, B_N), dim3(256), 0, stream>>>(z16, WVt, out);
}

// Round 9
// 596.819 us; speedup vs baseline: 1.5335x; 1.5335x over previous
//
#include <hip/hip_runtime.h>
#include <math.h>

namespace {
constexpr int B_N  = 32;
constexpr int SEQ  = 1024;
constexpr int AG   = 256;
constexpr int D    = 256;
constexpr int NH   = 8;
constexpr float SCALE = 0.0625f;
constexpr float EPS   = 1e-12f;

// workspace byte offsets (total ~88 MB)
constexpr size_t HHI_OFF  = 0;          // ushort(bf16) B*SEQ*D = 16 MB
constexpr size_t HLO_OFF  = 16777216;   // ushort(bf16) B*SEQ*D = 16 MB
constexpr size_t HT_OFF   = 33554432;   // ushort(bf16) B*D*SEQ = 16 MB
constexpr size_t MTHI_OFF = 50331648;   // ushort NH*D*D = 1 MB
constexpr size_t MTLO_OFF = 51380224;   // ushort NH*D*D = 1 MB
constexpr size_t MB_OFF   = 52428800;   // u32 B*AG*SEQ/32 = 1 MB
constexpr size_t WVT_OFF  = 53477376;   // ushort NH*D*D = 1 MB
constexpr size_t Z16_OFF  = 54525952;   // ushort B*NH*AG*D = 33.5 MB
}

typedef __attribute__((ext_vector_type(8))) short short8;
typedef __attribute__((ext_vector_type(4))) float floatx4;
#define MFMA_BF(A,B,C) __builtin_amdgcn_mfma_f32_16x16x32_bf16(A,B,C,0,0,0)

__device__ __forceinline__ unsigned short bf16_rtne(float f) {
    unsigned u = __float_as_uint(f);
    u += 0x7fffu + ((u >> 16) & 1u);
    return (unsigned short)(u >> 16);
}
__device__ __forceinline__ float bf16_tof(unsigned short h) {
    return __uint_as_float(((unsigned)h) << 16);
}
// async global->LDS DMA, 16 B/lane; LDS dst = wave-uniform base + lane*16
__device__ __forceinline__ void async16(void* lds, const void* g) {
    __builtin_amdgcn_global_load_lds(
        (const __attribute__((address_space(1))) unsigned int*)g,
        (__attribute__((address_space(3))) unsigned int*)lds,
        16, 0, 0);
}

// ---------------------------------------------------------------------------
// Encoder: h = lrelu(x)@W_enc^T + b -> h_hi, h_lo (bf16 split, [B,N,D])
// ---------------------------------------------------------------------------
__global__ __launch_bounds__(256) void enc_kernel(
    const float* __restrict__ x, const float* __restrict__ W_enc,
    const float* __restrict__ b_enc,
    ushort* __restrict__ h_hi, ushort* __restrict__ h_lo)
{
    __shared__ float AsT[32][68];
    __shared__ float BsT[32][68];
    const int t  = threadIdx.x;
    const int tx = t & 15, ty = t >> 4;
    const int col0 = blockIdx.x * 64;
    const int row0 = blockIdx.y * 64;

    float acc[4][4];
#pragma unroll
    for (int r = 0; r < 4; ++r)
#pragma unroll
        for (int c = 0; c < 4; ++c) acc[r][c] = 0.f;

    for (int k0 = 0; k0 < 256; k0 += 32) {
        __syncthreads();
#pragma unroll
        for (int ss = 0; ss < 2; ++ss) {
            int flat = t + 256 * ss;
            int rr = flat >> 3, k4 = flat & 7;
            float4 v = *(const float4*)(x + (size_t)(row0 + rr) * 256 + k0 + k4 * 4);
            v.x = v.x > 0.f ? v.x : 0.01f * v.x;
            v.y = v.y > 0.f ? v.y : 0.01f * v.y;
            v.z = v.z > 0.f ? v.z : 0.01f * v.z;
            v.w = v.w > 0.f ? v.w : 0.01f * v.w;
            AsT[k4*4+0][rr] = v.x; AsT[k4*4+1][rr] = v.y;
            AsT[k4*4+2][rr] = v.z; AsT[k4*4+3][rr] = v.w;
            float4 wv = *(const float4*)(W_enc + (size_t)(col0 + rr) * 256 + k0 + k4 * 4);
            BsT[k4*4+0][rr] = wv.x; BsT[k4*4+1][rr] = wv.y;
            BsT[k4*4+2][rr] = wv.z; BsT[k4*4+3][rr] = wv.w;
        }
        __syncthreads();
#pragma unroll 8
        for (int kk = 0; kk < 32; ++kk) {
            float4 a4 = *(const float4*)&AsT[kk][ty * 4];
            float4 b4 = *(const float4*)&BsT[kk][tx * 4];
            const float ar[4] = {a4.x, a4.y, a4.z, a4.w};
            const float bc[4] = {b4.x, b4.y, b4.z, b4.w};
#pragma unroll
            for (int r = 0; r < 4; ++r)
#pragma unroll
                for (int c = 0; c < 4; ++c)
                    acc[r][c] = fmaf(ar[r], bc[c], acc[r][c]);
        }
    }

    float4 bv = *(const float4*)(b_enc + col0 + tx * 4);
    const float bb4[4] = {bv.x, bv.y, bv.z, bv.w};
#pragma unroll
    for (int r = 0; r < 4; ++r) {
        const int row = row0 + ty * 4 + r;
        ushort hi4[4], lo4[4];
#pragma unroll
        for (int c = 0; c < 4; ++c) {
            float v = acc[r][c] + bb4[c];
            hi4[c] = bf16_rtne(v);
            lo4[c] = bf16_rtne(v - bf16_tof(hi4[c]));
        }
        *(ushort4*)(h_hi + (size_t)row * 256 + col0 + tx * 4) =
            make_ushort4(hi4[0], hi4[1], hi4[2], hi4[3]);
        *(ushort4*)(h_lo + (size_t)row * 256 + col0 + tx * 4) =
            make_ushort4(lo4[0], lo4[1], lo4[2], lo4[3]);
    }
}

// ---------------------------------------------------------------------------
// Fused prep: maskbits (vb<1024) | htrans (1024..3071) | wvt (3072..3199) |
// mprep (3200..3327).
// ---------------------------------------------------------------------------
__global__ __launch_bounds__(256) void prep_fused(
    const float* __restrict__ m, unsigned* __restrict__ mb,
    const ushort* __restrict__ h_hi, ushort* __restrict__ hT,
    const float* __restrict__ WV, ushort* __restrict__ WVt,
    const float* __restrict__ WQ, const float* __restrict__ WK,
    ushort* __restrict__ Mt_hi, ushort* __restrict__ Mt_lo)
{
    __shared__ __align__(16) char plds[17408];
    const int t = threadIdx.x;
    const int v = blockIdx.x;

    if (v < 1024) {
        // ---- maskbits
        const int idx = v * 256 + t;
        const float4* src = (const float4*)(m + (size_t)idx * 32);
        unsigned wbits = 0;
#pragma unroll
        for (int i = 0; i < 8; ++i) {
            float4 vv = src[i];
            wbits |= (vv.x > 0.5f ? 1u : 0u) << (i * 4 + 0);
            wbits |= (vv.y > 0.5f ? 1u : 0u) << (i * 4 + 1);
            wbits |= (vv.z > 0.5f ? 1u : 0u) << (i * 4 + 2);
            wbits |= (vv.w > 0.5f ? 1u : 0u) << (i * 4 + 3);
        }
        mb[idx] = wbits;
    } else if (v < 3072) {
        // ---- htrans: hT[b][d][n] = h_hi[b][n][d] (full coverage, 2 loads)
        ushort (*T)[72] = (ushort(*)[72])plds;   // 9216 B
        const int v1 = v - 1024;
        const int n0 = (v1 & 15) * 64, d0 = ((v1 >> 4) & 3) * 64, b = v1 >> 6;
        {
            const int r = t >> 2, c = (t & 3) * 16;
            const ushort* src = h_hi + ((size_t)(b * 1024 + n0 + r)) * 256 + d0 + c;
            *(short8*)&T[r][c]     = *(const short8*)src;
            *(short8*)&T[r][c + 8] = *(const short8*)(src + 8);
        }
        __syncthreads();
        {
            const int dd = t >> 2, seg = (t & 3) * 16;
            ushort tmp[16];
#pragma unroll
            for (int j = 0; j < 16; ++j) tmp[j] = T[seg + j][dd];
            ushort* dst = hT + ((size_t)(b * 256 + d0 + dd)) * 1024 + n0 + seg;
            *(short8*)dst       = *(short8*)&tmp[0];
            *(short8*)(dst + 8) = *(short8*)&tmp[8];
        }
    } else if (v < 3200) {
        // ---- wvt: WVt[h][e][d] = bf16(WV[h][d][e]); pitch 68 f32 (16B-align)
        float (*T)[68] = (float(*)[68])plds;     // 17408 B
        const int v2 = v - 3072;
        const int d0 = (v2 & 3) * 64, e0 = ((v2 >> 2) & 3) * 64, h = v2 >> 4;
        {
            const int r = t >> 2, c = (t & 3) * 16;
            const float* src = WV + ((size_t)(h * 256 + d0 + r)) * 256 + e0 + c;
#pragma unroll
            for (int j = 0; j < 4; ++j)
                *(float4*)&T[r][c + j * 4] = *(const float4*)(src + j * 4);
        }
        __syncthreads();
        {
            const int ee = t >> 2, seg = (t & 3) * 16;
            ushort tmp[16];
#pragma unroll
            for (int j = 0; j < 16; ++j) tmp[j] = bf16_rtne(T[seg + j][ee]);
            ushort* dst = WVt + ((size_t)(h * 256 + e0 + ee)) * 256 + d0 + seg;
            *(short8*)dst       = *(short8*)&tmp[0];
            *(short8*)(dst + 8) = *(short8*)&tmp[8];
        }
    } else {
        // ---- mprep: Mt_h[d'][d] = (WQ_h @ WK_h^T)[d][d'] -> bf16 hi/lo
        float (*AsT)[68] = (float(*)[68])plds;           // 8704 B
        float (*BsT)[68] = (float(*)[68])(plds + 8704);  // 8704 B
        const int v3 = v - 3200;
        const int tx = t & 15, ty = t >> 4;
        const int col0 = (v3 & 3) * 64;
        const int row0 = ((v3 >> 2) & 3) * 64;
        const int hz   = v3 >> 4;
        const float* A  = WK + (size_t)hz * 256 * 256;
        const float* Bm = WQ + (size_t)hz * 256 * 256;
        ushort* Chi = Mt_hi + (size_t)hz * 256 * 256;
        ushort* Clo = Mt_lo + (size_t)hz * 256 * 256;

        float acc[4][4];
#pragma unroll
        for (int r = 0; r < 4; ++r)
#pragma unroll
            for (int c = 0; c < 4; ++c) acc[r][c] = 0.f;

        for (int k0 = 0; k0 < 256; k0 += 32) {
            __syncthreads();
#pragma unroll
            for (int ss = 0; ss < 2; ++ss) {
                int flat = t + 256 * ss;
                int rr = flat >> 3, k4 = flat & 7;
                float4 vv = *(const float4*)(A + (size_t)(row0 + rr) * 256 + k0 + k4 * 4);
                AsT[k4*4+0][rr] = vv.x; AsT[k4*4+1][rr] = vv.y;
                AsT[k4*4+2][rr] = vv.z; AsT[k4*4+3][rr] = vv.w;
                float4 wv = *(const float4*)(Bm + (size_t)(col0 + rr) * 256 + k0 + k4 * 4);
                BsT[k4*4+0][rr] = wv.x; BsT[k4*4+1][rr] = wv.y;
                BsT[k4*4+2][rr] = wv.z; BsT[k4*4+3][rr] = wv.w;
            }
            __syncthreads();
#pragma unroll 8
            for (int kk = 0; kk < 32; ++kk) {
                float4 a4 = *(const float4*)&AsT[kk][ty * 4];
                float4 b4 = *(const float4*)&BsT[kk][tx * 4];
                const float ar[4] = {a4.x, a4.y, a4.z, a4.w};
                const float bc[4] = {b4.x, b4.y, b4.z, b4.w};
#pragma unroll
                for (int r = 0; r < 4; ++r)
#pragma unroll
                    for (int c = 0; c < 4; ++c)
                        acc[r][c] = fmaf(ar[r], bc[c], acc[r][c]);
            }
        }
#pragma unroll
        for (int r = 0; r < 4; ++r) {
            const int row = row0 + ty * 4 + r;
            ushort hi4[4], lo4[4];
#pragma unroll
            for (int c = 0; c < 4; ++c) {
                float vv = acc[r][c];
                hi4[c] = bf16_rtne(vv);
                lo4[c] = bf16_rtne(vv - bf16_tof(hi4[c]));
            }
            *(ushort4*)(Chi + (size_t)row * 256 + col0 + tx * 4) =
                make_ushort4(hi4[0], hi4[1], hi4[2], hi4[3]);
            *(ushort4*)(Clo + (size_t)row * 256 + col0 + tx * 4) =
                make_ushort4(lo4[0], lo4[1], lo4[2], lo4[3]);
        }
    }
}

// ---------------------------------------------------------------------------
// Attention v6b: R8's 2-heads-per-block tile sharing, with the launch-bounds
// bug fixed. R8's __launch_bounds__(512,4) capped VGPRs at 64 -> accumulator
// spills -> 2 GB scratch traffic, HBM-bound at 3 TB/s (measured). (512,2)
// caps at 256; per-wave code matches R7's 124-VGPR compile, so expect ~124
// and LDS (59.4 KB -> 2 blocks/CU) to set occupancy at 16 waves/CU.
// ---------------------------------------------------------------------------
__global__ __launch_bounds__(512, 2) void attn_mfma(
    const ushort* __restrict__ h_hi, const ushort* __restrict__ h_lo,
    const ushort* __restrict__ hT,   const ushort* __restrict__ Mt_hi,
    const ushort* __restrict__ Mt_lo, const unsigned* __restrict__ mbits,
    ushort* __restrict__ zout)
{
    __shared__ __align__(16) char lds[59392];
    ushort* hS_hi = (ushort*)lds;             // 16384 B
    ushort* hS_lo = (ushort*)(lds + 16384);   // 16384 B
    ushort* hTS   = (ushort*)(lds + 32768);   // 16384 B
    ushort* pP    = (ushort*)(lds + 49152);   // [128][40] bf16 = 10240 B

    const int t    = threadIdx.x;
    const int wv   = t >> 6;          // 0..7
    const int lane = t & 63;
    const int l15  = lane & 15;
    const int quad = lane >> 4;
    const int f    = blockIdx.x;      // 512 blocks
    const int b    = (f & 7) + 8 * (f >> 7);
    const int mid  = (f >> 3) & 15;
    const int hh   = (mid >> 2) * 2 + (wv >> 2);   // head per wave
    const int a0   = (mid & 3) * 64;
    const int aw   = a0 + (wv & 3) * 16;           // a-subtile per wave

    const ushort* hbh = h_hi + (size_t)b * SEQ * D;
    const ushort* hbl = h_lo + (size_t)b * SEQ * D;
    const ushort* hTb = hT   + (size_t)b * D * SEQ;

    // ---- Phase 0: Q' = ha @ Mt^T (split-bf16 x3), C-layout fp32 tiles
    floatx4 qac[16];
#pragma unroll
    for (int i = 0; i < 16; ++i) qac[i] = (floatx4){0.f, 0.f, 0.f, 0.f};

    for (int kc = 0; kc < 4; ++kc) {
        short8 Ah[2], Al[2];
#pragma unroll
        for (int kt = 0; kt < 2; ++kt) {
            const size_t ao = ((size_t)b * SEQ + aw + l15) * D +
                              kc * 64 + kt * 32 + quad * 8;
            Ah[kt] = *(const short8*)(h_hi + ao);
            Al[kt] = *(const short8*)(h_lo + ao);
        }
#pragma unroll
        for (int nt2 = 0; nt2 < 16; ++nt2) {
#pragma unroll
            for (int kt = 0; kt < 2; ++kt) {
                const size_t mo = ((size_t)hh * D + nt2 * 16 + l15) * D +
                                  kc * 64 + kt * 32 + quad * 8;
                short8 Bh = *(const short8*)(Mt_hi + mo);
                short8 Bl = *(const short8*)(Mt_lo + mo);
                qac[nt2] = MFMA_BF(Ah[kt], Bh, qac[nt2]);
                qac[nt2] = MFMA_BF(Al[kt], Bh, qac[nt2]);
                qac[nt2] = MFMA_BF(Ah[kt], Bl, qac[nt2]);
            }
        }
    }

    // repack Q' C-layout -> bf16 hi/lo A-frags via fp32 scratch overlapping
    // the tile region (rows wv*16.., pitch 68 f32 = 34.8 KB < 48 KB; all
    // pre-loop scratch — the first barrier precedes the first DMA).
    short8 Qhi[8], Qlo[8];
    {
        float* qscr = (float*)lds;
        for (int c = 0; c < 4; ++c) {
#pragma unroll
            for (int j = 0; j < 4; ++j)
#pragma unroll
                for (int r = 0; r < 4; ++r)
                    qscr[(wv * 16 + quad * 4 + r) * 68 + j * 16 + l15] = qac[c * 4 + j][r];
#pragma unroll
            for (int kt = 0; kt < 2; ++kt) {
                const float* pr = &qscr[(wv * 16 + l15) * 68 + kt * 32 + quad * 8];
                float ftmp[8];
                *(float4*)&ftmp[0] = *(const float4*)pr;
                *(float4*)&ftmp[4] = *(const float4*)(pr + 4);
                short8 hi, lo;
#pragma unroll
                for (int e = 0; e < 8; ++e) {
                    unsigned short hb = bf16_rtne(ftmp[e]);
                    hi[e] = (short)hb;
                    lo[e] = (short)bf16_rtne(ftmp[e] - bf16_tof(hb));
                }
                Qhi[c * 2 + kt] = hi;
                Qlo[c * 2 + kt] = lo;
            }
        }
    }

    // ---- Phase 1: flash loop over 32 n-tiles of 32 rows
    floatx4 zac[16];
#pragma unroll
    for (int i = 0; i < 16; ++i) zac[i] = (floatx4){0.f, 0.f, 0.f, 0.f};
    float mx[4] = {-INFINITY, -INFINITY, -INFINITY, -INFINITY};
    float Za[4] = {0.f, 0.f, 0.f, 0.f};
    float Zm[4] = {0.f, 0.f, 0.f, 0.f};

    for (int nt = 0; nt < 32; ++nt) {
        const int n0 = nt * 32;
        __syncthreads();   // prior-tile reads done (also fences Q' scratch)

        // DMA hS_hi / hS_lo: 1024 slots x 16B, spread over 8 waves (2 ea.)
#pragma unroll
        for (int i = 0; i < 2; ++i) {
            const int slot = wv * 128 + i * 64 + lane;
            const int row  = slot >> 5;
            const int p    = slot & 31;
            const int c    = p ^ (row & 7);
            const size_t go = (size_t)(n0 + row) * 256 + c * 8;
            const size_t lo_ = (size_t)(wv * 128 + i * 64) * 8;
            async16(hS_hi + lo_, hbh + go);
            async16(hS_lo + lo_, hbl + go);
        }
        // DMA hTS: row(d) = slot>>2, p = slot&3, c = p ^ ((row>>2)&3)
#pragma unroll
        for (int i = 0; i < 2; ++i) {
            const int slot = wv * 128 + i * 64 + lane;
            const int row  = slot >> 2;
            const int p    = slot & 3;
            const int c    = p ^ ((row >> 2) & 3);
            async16(hTS + (size_t)(wv * 128 + i * 64) * 8,
                    hTb + (size_t)row * 1024 + n0 + c * 8);
        }
        __syncthreads();   // vmcnt drain -> tiles resident

        // S = Q' @ h^T  (split-bf16 x3; swizzled b128 reads)
        floatx4 sac[2];
        sac[0] = (floatx4){0.f, 0.f, 0.f, 0.f};
        sac[1] = (floatx4){0.f, 0.f, 0.f, 0.f};
#pragma unroll
        for (int ks = 0; ks < 8; ++ks) {
            const int cg = ks * 4 + quad;
#pragma unroll
            for (int ntile = 0; ntile < 2; ++ntile) {
                const int row = ntile * 16 + l15;
                const int off = row * 256 + (cg ^ (row & 7)) * 8;
                short8 Bh = *(const short8*)&hS_hi[off];
                short8 Bl = *(const short8*)&hS_lo[off];
                sac[ntile] = MFMA_BF(Qhi[ks], Bh, sac[ntile]);
                sac[ntile] = MFMA_BF(Qlo[ks], Bh, sac[ntile]);
                sac[ntile] = MFMA_BF(Qhi[ks], Bl, sac[ntile]);
            }
        }

        // online masked softmax (row a = aw + 4*quad + r)
        float alr[4];
#pragma unroll
        for (int r = 0; r < 4; ++r) {
            const int a = aw + quad * 4 + r;
            const unsigned w0 = mbits[((size_t)b * AG + a) * (SEQ / 32) + nt];
            float l0 = sac[0][r] * SCALE, l1 = sac[1][r] * SCALE;
            float mt = fmaxf(l0, l1);
#pragma unroll
            for (int off = 1; off < 16; off <<= 1) mt = fmaxf(mt, __shfl_xor(mt, off));
            const float mxn = fmaxf(mx[r], mt);
            const float al  = __expf(mx[r] - mxn);
            float e0 = __expf(l0 - mxn), e1 = __expf(l1 - mxn);
            float p0 = ((w0 >> l15) & 1u)        ? e0 : 0.f;
            float p1 = ((w0 >> (16 + l15)) & 1u) ? e1 : 0.f;
            float za = e0 + e1;
            float zm = p0 + p1;
#pragma unroll
            for (int off = 1; off < 16; off <<= 1) {
                za += __shfl_xor(za, off);
                zm += __shfl_xor(zm, off);
            }
            Za[r] = Za[r] * al + za;
            Zm[r] = Zm[r] * al + zm;
            mx[r] = mxn;
            pP[(wv * 16 + quad * 4 + r) * 40 + l15]      = bf16_rtne(p0);
            pP[(wv * 16 + quad * 4 + r) * 40 + 16 + l15] = bf16_rtne(p1);
            alr[r] = al;
        }
#pragma unroll
        for (int dt = 0; dt < 16; ++dt) {
            zac[dt][0] *= alr[0]; zac[dt][1] *= alr[1];
            zac[dt][2] *= alr[2]; zac[dt][3] *= alr[3];
        }

        // z += P @ h : P A-frag (wave-private pP), hTS B-frags (swizzled)
        short8 Pf = *(const short8*)&pP[(wv * 16 + l15) * 40 + quad * 8];
#pragma unroll
        for (int dt = 0; dt < 16; ++dt) {
            const int row = dt * 16 + l15;
            const int p   = quad ^ ((row >> 2) & 3);
            short8 Bf = *(const short8*)&hTS[row * 32 + p * 8];
            zac[dt] = MFMA_BF(Pf, Bf, zac[dt]);
        }
    }

    // epilogue: z_bf16 = z / (Zm + EPS*Za)
#pragma unroll
    for (int r = 0; r < 4; ++r) {
        const int a = aw + quad * 4 + r;
        const float inv = 1.0f / (Zm[r] + EPS * Za[r]);
        ushort* zr = zout + (((size_t)b * NH + hh) * AG + a) * D;
#pragma unroll
        for (int dt = 0; dt < 16; ++dt)
            zr[dt * 16 + l15] = bf16_rtne(zac[dt][r] * inv);
    }
}

// ---------------------------------------------------------------------------
// out[b,a,e] = (1/8) * sum_{h,d} z[b,h,a,d] * WVt[h,e,d]   (bf16 MFMA, K=2048)
// ---------------------------------------------------------------------------
__global__ __launch_bounds__(256) void out_mfma(
    const ushort* __restrict__ z16, const ushort* __restrict__ WVt,
    float* __restrict__ out)
{
    const int t    = threadIdx.x;
    const int wv   = t >> 6;
    const int lane = t & 63;
    const int l15  = lane & 15;
    const int quad = lane >> 4;
    const int e0 = blockIdx.x * 64;
    const int a0 = blockIdx.y * 64;
    const int b  = blockIdx.z;
    const int aw = a0 + wv * 16;

    floatx4 acc[4];
#pragma unroll
    for (int i = 0; i < 4; ++i) acc[i] = (floatx4){0.f, 0.f, 0.f, 0.f};

#pragma unroll 4
    for (int c = 0; c < 64; ++c) {
        const int hh = c >> 3, d0 = (c & 7) * 32;
        short8 Af = *(const short8*)(z16 +
            (((size_t)b * NH + hh) * AG + aw + l15) * D + d0 + quad * 8);
#pragma unroll
        for (int et = 0; et < 4; ++et) {
            short8 Bf = *(const short8*)(WVt +
                ((size_t)hh * D + e0 + et * 16 + l15) * D + d0 + quad * 8);
            acc[et] = MFMA_BF(Af, Bf, acc[et]);
        }
    }
#pragma unroll
    for (int et = 0; et < 4; ++et)
#pragma unroll
        for (int r = 0; r < 4; ++r)
            out[((size_t)b * AG + aw + quad * 4 + r) * D + e0 + et * 16 + l15] =
                acc[et][r] * 0.125f;
}

// ---------------------------------------------------------------------------
extern "C" void kernel_launch(void* const* d_in, const int* in_sizes, int n_in,
                              void* d_out, int out_size, void* d_ws, size_t ws_size,
                              hipStream_t stream)
{
    (void)in_sizes; (void)n_in; (void)out_size; (void)ws_size;
    const float* x     = (const float*)d_in[0];
    const float* m     = (const float*)d_in[1];
    const float* W_enc = (const float*)d_in[2];
    const float* b_enc = (const float*)d_in[3];
    const float* WQ    = (const float*)d_in[4];
    const float* WK    = (const float*)d_in[5];
    const float* WV    = (const float*)d_in[6];
    float* out = (float*)d_out;
    char* ws = (char*)d_ws;

    ushort*   h_hi  = (ushort*)(ws + HHI_OFF);
    ushort*   h_lo  = (ushort*)(ws + HLO_OFF);
    ushort*   hT    = (ushort*)(ws + HT_OFF);
    ushort*   Mt_hi = (ushort*)(ws + MTHI_OFF);
    ushort*   Mt_lo = (ushort*)(ws + MTLO_OFF);
    unsigned* mbits = (unsigned*)(ws + MB_OFF);
    ushort*   WVt   = (ushort*)(ws + WVT_OFF);
    ushort*   z16   = (ushort*)(ws + Z16_OFF);

    enc_kernel<<<dim3(4, 512, 1), dim3(256), 0, stream>>>(
        x, W_enc, b_enc, h_hi, h_lo);
    prep_fused<<<dim3(3328, 1, 1), dim3(256), 0, stream>>>(
        m, mbits, h_hi, hT, WV, WVt, WQ, WK, Mt_hi, Mt_lo);
    attn_mfma<<<dim3(512, 1, 1), dim3(512), 0, stream>>>(
        h_hi, h_lo, hT, Mt_hi, Mt_lo, mbits, z16);
    out_mfma<<<dim3(4, 4, B_N), dim3(256), 0, stream>>>(z16, WVt, out);
}

// Round 10
// 575.429 us; speedup vs baseline: 1.5905x; 1.0372x over previous
//
#include <hip/hip_runtime.h>
#include <math.h>

namespace {
constexpr int B_N  = 32;
constexpr int SEQ  = 1024;
constexpr int AG   = 256;
constexpr int D    = 256;
constexpr int NH   = 8;
constexpr float SCALE = 0.0625f;
constexpr float EPS   = 1e-12f;

// workspace byte offsets (total ~88 MB)
constexpr size_t HHI_OFF  = 0;          // ushort(bf16) B*SEQ*D = 16 MB
constexpr size_t HLO_OFF  = 16777216;   // ushort(bf16) B*SEQ*D = 16 MB
constexpr size_t HT_OFF   = 33554432;   // ushort(bf16) B*D*SEQ = 16 MB
constexpr size_t MTHI_OFF = 50331648;   // ushort NH*D*D = 1 MB
constexpr size_t MTLO_OFF = 51380224;   // ushort NH*D*D = 1 MB
constexpr size_t MB_OFF   = 52428800;   // u32 B*AG*SEQ/32 = 1 MB
constexpr size_t WVT_OFF  = 53477376;   // ushort NH*D*D = 1 MB
constexpr size_t Z16_OFF  = 54525952;   // ushort B*NH*AG*D = 33.5 MB
}

typedef __attribute__((ext_vector_type(8))) short short8;
typedef __attribute__((ext_vector_type(4))) float floatx4;
#define MFMA_BF(A,B,C) __builtin_amdgcn_mfma_f32_16x16x32_bf16(A,B,C,0,0,0)

__device__ __forceinline__ unsigned short bf16_rtne(float f) {
    unsigned u = __float_as_uint(f);
    u += 0x7fffu + ((u >> 16) & 1u);
    return (unsigned short)(u >> 16);
}
__device__ __forceinline__ float bf16_tof(unsigned short h) {
    return __uint_as_float(((unsigned)h) << 16);
}
// async global->LDS DMA, 16 B/lane; LDS dst = wave-uniform base + lane*16
__device__ __forceinline__ void async16(void* lds, const void* g) {
    __builtin_amdgcn_global_load_lds(
        (const __attribute__((address_space(1))) unsigned int*)g,
        (__attribute__((address_space(3))) unsigned int*)lds,
        16, 0, 0);
}

// ---------------------------------------------------------------------------
// Encoder: h = lrelu(x)@W_enc^T + b -> h_hi, h_lo (bf16 split, [B,N,D])
// ---------------------------------------------------------------------------
__global__ __launch_bounds__(256) void enc_kernel(
    const float* __restrict__ x, const float* __restrict__ W_enc,
    const float* __restrict__ b_enc,
    ushort* __restrict__ h_hi, ushort* __restrict__ h_lo)
{
    __shared__ float AsT[32][68];
    __shared__ float BsT[32][68];
    const int t  = threadIdx.x;
    const int tx = t & 15, ty = t >> 4;
    const int col0 = blockIdx.x * 64;
    const int row0 = blockIdx.y * 64;

    float acc[4][4];
#pragma unroll
    for (int r = 0; r < 4; ++r)
#pragma unroll
        for (int c = 0; c < 4; ++c) acc[r][c] = 0.f;

    for (int k0 = 0; k0 < 256; k0 += 32) {
        __syncthreads();
#pragma unroll
        for (int ss = 0; ss < 2; ++ss) {
            int flat = t + 256 * ss;
            int rr = flat >> 3, k4 = flat & 7;
            float4 v = *(const float4*)(x + (size_t)(row0 + rr) * 256 + k0 + k4 * 4);
            v.x = v.x > 0.f ? v.x : 0.01f * v.x;
            v.y = v.y > 0.f ? v.y : 0.01f * v.y;
            v.z = v.z > 0.f ? v.z : 0.01f * v.z;
            v.w = v.w > 0.f ? v.w : 0.01f * v.w;
            AsT[k4*4+0][rr] = v.x; AsT[k4*4+1][rr] = v.y;
            AsT[k4*4+2][rr] = v.z; AsT[k4*4+3][rr] = v.w;
            float4 wv = *(const float4*)(W_enc + (size_t)(col0 + rr) * 256 + k0 + k4 * 4);
            BsT[k4*4+0][rr] = wv.x; BsT[k4*4+1][rr] = wv.y;
            BsT[k4*4+2][rr] = wv.z; BsT[k4*4+3][rr] = wv.w;
        }
        __syncthreads();
#pragma unroll 8
        for (int kk = 0; kk < 32; ++kk) {
            float4 a4 = *(const float4*)&AsT[kk][ty * 4];
            float4 b4 = *(const float4*)&BsT[kk][tx * 4];
            const float ar[4] = {a4.x, a4.y, a4.z, a4.w};
            const float bc[4] = {b4.x, b4.y, b4.z, b4.w};
#pragma unroll
            for (int r = 0; r < 4; ++r)
#pragma unroll
                for (int c = 0; c < 4; ++c)
                    acc[r][c] = fmaf(ar[r], bc[c], acc[r][c]);
        }
    }

    float4 bv = *(const float4*)(b_enc + col0 + tx * 4);
    const float bb4[4] = {bv.x, bv.y, bv.z, bv.w};
#pragma unroll
    for (int r = 0; r < 4; ++r) {
        const int row = row0 + ty * 4 + r;
        ushort hi4[4], lo4[4];
#pragma unroll
        for (int c = 0; c < 4; ++c) {
            float v = acc[r][c] + bb4[c];
            hi4[c] = bf16_rtne(v);
            lo4[c] = bf16_rtne(v - bf16_tof(hi4[c]));
        }
        *(ushort4*)(h_hi + (size_t)row * 256 + col0 + tx * 4) =
            make_ushort4(hi4[0], hi4[1], hi4[2], hi4[3]);
        *(ushort4*)(h_lo + (size_t)row * 256 + col0 + tx * 4) =
            make_ushort4(lo4[0], lo4[1], lo4[2], lo4[3]);
    }
}

// ---------------------------------------------------------------------------
// Fused prep: maskbits (vb<1024) | htrans (1024..3071) | wvt (3072..3199) |
// mprep (3200..3327).
// ---------------------------------------------------------------------------
__global__ __launch_bounds__(256) void prep_fused(
    const float* __restrict__ m, unsigned* __restrict__ mb,
    const ushort* __restrict__ h_hi, ushort* __restrict__ hT,
    const float* __restrict__ WV, ushort* __restrict__ WVt,
    const float* __restrict__ WQ, const float* __restrict__ WK,
    ushort* __restrict__ Mt_hi, ushort* __restrict__ Mt_lo)
{
    __shared__ __align__(16) char plds[17408];
    const int t = threadIdx.x;
    const int v = blockIdx.x;

    if (v < 1024) {
        // ---- maskbits
        const int idx = v * 256 + t;
        const float4* src = (const float4*)(m + (size_t)idx * 32);
        unsigned wbits = 0;
#pragma unroll
        for (int i = 0; i < 8; ++i) {
            float4 vv = src[i];
            wbits |= (vv.x > 0.5f ? 1u : 0u) << (i * 4 + 0);
            wbits |= (vv.y > 0.5f ? 1u : 0u) << (i * 4 + 1);
            wbits |= (vv.z > 0.5f ? 1u : 0u) << (i * 4 + 2);
            wbits |= (vv.w > 0.5f ? 1u : 0u) << (i * 4 + 3);
        }
        mb[idx] = wbits;
    } else if (v < 3072) {
        // ---- htrans: hT[b][d][n] = h_hi[b][n][d] (full coverage, 2 loads)
        ushort (*T)[72] = (ushort(*)[72])plds;   // 9216 B
        const int v1 = v - 1024;
        const int n0 = (v1 & 15) * 64, d0 = ((v1 >> 4) & 3) * 64, b = v1 >> 6;
        {
            const int r = t >> 2, c = (t & 3) * 16;
            const ushort* src = h_hi + ((size_t)(b * 1024 + n0 + r)) * 256 + d0 + c;
            *(short8*)&T[r][c]     = *(const short8*)src;
            *(short8*)&T[r][c + 8] = *(const short8*)(src + 8);
        }
        __syncthreads();
        {
            const int dd = t >> 2, seg = (t & 3) * 16;
            ushort tmp[16];
#pragma unroll
            for (int j = 0; j < 16; ++j) tmp[j] = T[seg + j][dd];
            ushort* dst = hT + ((size_t)(b * 256 + d0 + dd)) * 1024 + n0 + seg;
            *(short8*)dst       = *(short8*)&tmp[0];
            *(short8*)(dst + 8) = *(short8*)&tmp[8];
        }
    } else if (v < 3200) {
        // ---- wvt: WVt[h][e][d] = bf16(WV[h][d][e]); pitch 68 f32 (16B-align)
        float (*T)[68] = (float(*)[68])plds;     // 17408 B
        const int v2 = v - 3072;
        const int d0 = (v2 & 3) * 64, e0 = ((v2 >> 2) & 3) * 64, h = v2 >> 4;
        {
            const int r = t >> 2, c = (t & 3) * 16;
            const float* src = WV + ((size_t)(h * 256 + d0 + r)) * 256 + e0 + c;
#pragma unroll
            for (int j = 0; j < 4; ++j)
                *(float4*)&T[r][c + j * 4] = *(const float4*)(src + j * 4);
        }
        __syncthreads();
        {
            const int ee = t >> 2, seg = (t & 3) * 16;
            ushort tmp[16];
#pragma unroll
            for (int j = 0; j < 16; ++j) tmp[j] = bf16_rtne(T[seg + j][ee]);
            ushort* dst = WVt + ((size_t)(h * 256 + e0 + ee)) * 256 + d0 + seg;
            *(short8*)dst       = *(short8*)&tmp[0];
            *(short8*)(dst + 8) = *(short8*)&tmp[8];
        }
    } else {
        // ---- mprep: Mt_h[d'][d] = (WQ_h @ WK_h^T)[d][d'] -> bf16 hi/lo
        float (*AsT)[68] = (float(*)[68])plds;           // 8704 B
        float (*BsT)[68] = (float(*)[68])(plds + 8704);  // 8704 B
        const int v3 = v - 3200;
        const int tx = t & 15, ty = t >> 4;
        const int col0 = (v3 & 3) * 64;
        const int row0 = ((v3 >> 2) & 3) * 64;
        const int hz   = v3 >> 4;
        const float* A  = WK + (size_t)hz * 256 * 256;
        const float* Bm = WQ + (size_t)hz * 256 * 256;
        ushort* Chi = Mt_hi + (size_t)hz * 256 * 256;
        ushort* Clo = Mt_lo + (size_t)hz * 256 * 256;

        float acc[4][4];
#pragma unroll
        for (int r = 0; r < 4; ++r)
#pragma unroll
            for (int c = 0; c < 4; ++c) acc[r][c] = 0.f;

        for (int k0 = 0; k0 < 256; k0 += 32) {
            __syncthreads();
#pragma unroll
            for (int ss = 0; ss < 2; ++ss) {
                int flat = t + 256 * ss;
                int rr = flat >> 3, k4 = flat & 7;
                float4 vv = *(const float4*)(A + (size_t)(row0 + rr) * 256 + k0 + k4 * 4);
                AsT[k4*4+0][rr] = vv.x; AsT[k4*4+1][rr] = vv.y;
                AsT[k4*4+2][rr] = vv.z; AsT[k4*4+3][rr] = vv.w;
                float4 wv = *(const float4*)(Bm + (size_t)(col0 + rr) * 256 + k0 + k4 * 4);
                BsT[k4*4+0][rr] = wv.x; BsT[k4*4+1][rr] = wv.y;
                BsT[k4*4+2][rr] = wv.z; BsT[k4*4+3][rr] = wv.w;
            }
            __syncthreads();
#pragma unroll 8
            for (int kk = 0; kk < 32; ++kk) {
                float4 a4 = *(const float4*)&AsT[kk][ty * 4];
                float4 b4 = *(const float4*)&BsT[kk][tx * 4];
                const float ar[4] = {a4.x, a4.y, a4.z, a4.w};
                const float bc[4] = {b4.x, b4.y, b4.z, b4.w};
#pragma unroll
                for (int r = 0; r < 4; ++r)
#pragma unroll
                    for (int c = 0; c < 4; ++c)
                        acc[r][c] = fmaf(ar[r], bc[c], acc[r][c]);
            }
        }
#pragma unroll
        for (int r = 0; r < 4; ++r) {
            const int row = row0 + ty * 4 + r;
            ushort hi4[4], lo4[4];
#pragma unroll
            for (int c = 0; c < 4; ++c) {
                float vv = acc[r][c];
                hi4[c] = bf16_rtne(vv);
                lo4[c] = bf16_rtne(vv - bf16_tof(hi4[c]));
            }
            *(ushort4*)(Chi + (size_t)row * 256 + col0 + tx * 4) =
                make_ushort4(hi4[0], hi4[1], hi4[2], hi4[3]);
            *(ushort4*)(Clo + (size_t)row * 256 + col0 + tx * 4) =
                make_ushort4(lo4[0], lo4[1], lo4[2], lo4[3]);
        }
    }
}

// ---------------------------------------------------------------------------
// Attention v7: DOUBLE-BUFFERED DMA prefetch. Registers (VGPR+AGPR ~200/wave)
// cap residency at 1 block/CU regardless of LDS, so doubling the tile
// buffers (106 KB total) is free. Pipeline: prologue DMAs tiles 0,1; each
// iteration computes buf[nt&1], barriers (the vmcnt drain now hits a DMA
// issued a FULL ITERATION earlier), then issues tile nt+2 into the vacated
// buffer. One barrier/iter; no barrier waits on a just-issued DMA.
// Numerics identical to R7/R9 (proven: split-bf16 S, bf16 P/PV).
// ---------------------------------------------------------------------------
__global__ __launch_bounds__(512, 2) void attn_mfma(
    const ushort* __restrict__ h_hi, const ushort* __restrict__ h_lo,
    const ushort* __restrict__ hT,   const ushort* __restrict__ Mt_hi,
    const ushort* __restrict__ Mt_lo, const unsigned* __restrict__ mbits,
    ushort* __restrict__ zout)
{
    // buf k at k*49152: hS_hi 16384 | hS_lo 16384 | hTS 16384 ; pP at 98304
    __shared__ __align__(16) char lds[108544];
    ushort* pP = (ushort*)(lds + 98304);   // [128][40] bf16 = 10240 B

    const int t    = threadIdx.x;
    const int wv   = t >> 6;          // 0..7
    const int lane = t & 63;
    const int l15  = lane & 15;
    const int quad = lane >> 4;
    const int f    = blockIdx.x;      // 512 blocks
    const int b    = (f & 7) + 8 * (f >> 7);
    const int mid  = (f >> 3) & 15;
    const int hh   = (mid >> 2) * 2 + (wv >> 2);   // head per wave
    const int a0   = (mid & 3) * 64;
    const int aw   = a0 + (wv & 3) * 16;           // a-subtile per wave

    const ushort* hbh = h_hi + (size_t)b * SEQ * D;
    const ushort* hbl = h_lo + (size_t)b * SEQ * D;
    const ushort* hTb = hT   + (size_t)b * D * SEQ;

    // ---- Phase 0: Q' = ha @ Mt^T (split-bf16 x3), C-layout fp32 tiles
    floatx4 qac[16];
#pragma unroll
    for (int i = 0; i < 16; ++i) qac[i] = (floatx4){0.f, 0.f, 0.f, 0.f};

    for (int kc = 0; kc < 4; ++kc) {
        short8 Ah[2], Al[2];
#pragma unroll
        for (int kt = 0; kt < 2; ++kt) {
            const size_t ao = ((size_t)b * SEQ + aw + l15) * D +
                              kc * 64 + kt * 32 + quad * 8;
            Ah[kt] = *(const short8*)(h_hi + ao);
            Al[kt] = *(const short8*)(h_lo + ao);
        }
#pragma unroll
        for (int nt2 = 0; nt2 < 16; ++nt2) {
#pragma unroll
            for (int kt = 0; kt < 2; ++kt) {
                const size_t mo = ((size_t)hh * D + nt2 * 16 + l15) * D +
                                  kc * 64 + kt * 32 + quad * 8;
                short8 Bh = *(const short8*)(Mt_hi + mo);
                short8 Bl = *(const short8*)(Mt_lo + mo);
                qac[nt2] = MFMA_BF(Ah[kt], Bh, qac[nt2]);
                qac[nt2] = MFMA_BF(Al[kt], Bh, qac[nt2]);
                qac[nt2] = MFMA_BF(Ah[kt], Bl, qac[nt2]);
            }
        }
    }

    // repack Q' C-layout -> bf16 hi/lo A-frags via fp32 scratch in buf0
    // (wave-private rows, pitch 68 f32; 34.8 KB < 49 KB buf0)
    short8 Qhi[8], Qlo[8];
    {
        float* qscr = (float*)lds;
        for (int c = 0; c < 4; ++c) {
#pragma unroll
            for (int j = 0; j < 4; ++j)
#pragma unroll
                for (int r = 0; r < 4; ++r)
                    qscr[(wv * 16 + quad * 4 + r) * 68 + j * 16 + l15] = qac[c * 4 + j][r];
#pragma unroll
            for (int kt = 0; kt < 2; ++kt) {
                const float* pr = &qscr[(wv * 16 + l15) * 68 + kt * 32 + quad * 8];
                float ftmp[8];
                *(float4*)&ftmp[0] = *(const float4*)pr;
                *(float4*)&ftmp[4] = *(const float4*)(pr + 4);
                short8 hi, lo;
#pragma unroll
                for (int e = 0; e < 8; ++e) {
                    unsigned short hb = bf16_rtne(ftmp[e]);
                    hi[e] = (short)hb;
                    lo[e] = (short)bf16_rtne(ftmp[e] - bf16_tof(hb));
                }
                Qhi[c * 2 + kt] = hi;
                Qlo[c * 2 + kt] = lo;
            }
        }
    }
    __syncthreads();   // all waves done with Q' scratch before DMA into buf0

    // ---- DMA issue helper (tile n0 -> buf)
    auto issue_tile = [&](char* buf, int n0) {
        ushort* dh = (ushort*)buf;
        ushort* dl = (ushort*)(buf + 16384);
        ushort* dT = (ushort*)(buf + 32768);
#pragma unroll
        for (int i = 0; i < 2; ++i) {
            const int slot = wv * 128 + i * 64 + lane;
            const int row  = slot >> 5;
            const int p    = slot & 31;
            const int c    = p ^ (row & 7);
            const size_t go = (size_t)(n0 + row) * 256 + c * 8;
            const size_t lo_ = (size_t)(wv * 128 + i * 64) * 8;
            async16(dh + lo_, hbh + go);
            async16(dl + lo_, hbl + go);
        }
#pragma unroll
        for (int i = 0; i < 2; ++i) {
            const int slot = wv * 128 + i * 64 + lane;
            const int row  = slot >> 2;
            const int p    = slot & 3;
            const int c    = p ^ ((row >> 2) & 3);
            async16(dT + (size_t)(wv * 128 + i * 64) * 8,
                    hTb + (size_t)row * 1024 + n0 + c * 8);
        }
    };

    // prologue: tiles 0 and 1 in flight, then drain once
    issue_tile(lds,         0);
    issue_tile(lds + 49152, 32);
    __syncthreads();

    // ---- Phase 1: pipelined flash loop over 32 n-tiles of 32 rows
    floatx4 zac[16];
#pragma unroll
    for (int i = 0; i < 16; ++i) zac[i] = (floatx4){0.f, 0.f, 0.f, 0.f};
    float mx[4] = {-INFINITY, -INFINITY, -INFINITY, -INFINITY};
    float Za[4] = {0.f, 0.f, 0.f, 0.f};
    float Zm[4] = {0.f, 0.f, 0.f, 0.f};

    for (int nt = 0; nt < 32; ++nt) {
        const int n0 = nt * 32;
        char* cur = lds + (size_t)(nt & 1) * 49152;
        ushort* hS_hi = (ushort*)cur;
        ushort* hS_lo = (ushort*)(cur + 16384);
        ushort* hTS   = (ushort*)(cur + 32768);

        // S = Q' @ h^T  (split-bf16 x3; swizzled b128 reads)
        floatx4 sac[2];
        sac[0] = (floatx4){0.f, 0.f, 0.f, 0.f};
        sac[1] = (floatx4){0.f, 0.f, 0.f, 0.f};
#pragma unroll
        for (int ks = 0; ks < 8; ++ks) {
            const int cg = ks * 4 + quad;
#pragma unroll
            for (int ntile = 0; ntile < 2; ++ntile) {
                const int row = ntile * 16 + l15;
                const int off = row * 256 + (cg ^ (row & 7)) * 8;
                short8 Bh = *(const short8*)&hS_hi[off];
                short8 Bl = *(const short8*)&hS_lo[off];
                sac[ntile] = MFMA_BF(Qhi[ks], Bh, sac[ntile]);
                sac[ntile] = MFMA_BF(Qlo[ks], Bh, sac[ntile]);
                sac[ntile] = MFMA_BF(Qhi[ks], Bl, sac[ntile]);
            }
        }

        // online masked softmax (row a = aw + 4*quad + r)
        float alr[4];
#pragma unroll
        for (int r = 0; r < 4; ++r) {
            const int a = aw + quad * 4 + r;
            const unsigned w0 = mbits[((size_t)b * AG + a) * (SEQ / 32) + nt];
            float l0 = sac[0][r] * SCALE, l1 = sac[1][r] * SCALE;
            float mt = fmaxf(l0, l1);
#pragma unroll
            for (int off = 1; off < 16; off <<= 1) mt = fmaxf(mt, __shfl_xor(mt, off));
            const float mxn = fmaxf(mx[r], mt);
            const float al  = __expf(mx[r] - mxn);
            float e0 = __expf(l0 - mxn), e1 = __expf(l1 - mxn);
            float p0 = ((w0 >> l15) & 1u)        ? e0 : 0.f;
            float p1 = ((w0 >> (16 + l15)) & 1u) ? e1 : 0.f;
            float za = e0 + e1;
            float zm = p0 + p1;
#pragma unroll
            for (int off = 1; off < 16; off <<= 1) {
                za += __shfl_xor(za, off);
                zm += __shfl_xor(zm, off);
            }
            Za[r] = Za[r] * al + za;
            Zm[r] = Zm[r] * al + zm;
            mx[r] = mxn;
            pP[(wv * 16 + quad * 4 + r) * 40 + l15]      = bf16_rtne(p0);
            pP[(wv * 16 + quad * 4 + r) * 40 + 16 + l15] = bf16_rtne(p1);
            alr[r] = al;
        }
#pragma unroll
        for (int dt = 0; dt < 16; ++dt) {
            zac[dt][0] *= alr[0]; zac[dt][1] *= alr[1];
            zac[dt][2] *= alr[2]; zac[dt][3] *= alr[3];
        }

        // z += P @ h : P A-frag (wave-private pP), hTS B-frags (swizzled)
        short8 Pf = *(const short8*)&pP[(wv * 16 + l15) * 40 + quad * 8];
#pragma unroll
        for (int dt = 0; dt < 16; ++dt) {
            const int row = dt * 16 + l15;
            const int p   = quad ^ ((row >> 2) & 3);
            short8 Bf = *(const short8*)&hTS[row * 32 + p * 8];
            zac[dt] = MFMA_BF(Pf, Bf, zac[dt]);
        }

        // barrier: everyone done reading cur; DMA(nt+1) — issued one full
        // iteration ago — drains here with a tile's worth of slack.
        __syncthreads();
        if (nt + 2 < 32) issue_tile(cur, (nt + 2) * 32);
    }

    // epilogue: z_bf16 = z / (Zm + EPS*Za)
#pragma unroll
    for (int r = 0; r < 4; ++r) {
        const int a = aw + quad * 4 + r;
        const float inv = 1.0f / (Zm[r] + EPS * Za[r]);
        ushort* zr = zout + (((size_t)b * NH + hh) * AG + a) * D;
#pragma unroll
        for (int dt = 0; dt < 16; ++dt)
            zr[dt * 16 + l15] = bf16_rtne(zac[dt][r] * inv);
    }
}

// ---------------------------------------------------------------------------
// out[b,a,e] = (1/8) * sum_{h,d} z[b,h,a,d] * WVt[h,e,d]   (bf16 MFMA, K=2048)
// ---------------------------------------------------------------------------
__global__ __launch_bounds__(256) void out_mfma(
    const ushort* __restrict__ z16, const ushort* __restrict__ WVt,
    float* __restrict__ out)
{
    const int t    = threadIdx.x;
    const int wv   = t >> 6;
    const int lane = t & 63;
    const int l15  = lane & 15;
    const int quad = lane >> 4;
    const int e0 = blockIdx.x * 64;
    const int a0 = blockIdx.y * 64;
    const int b  = blockIdx.z;
    const int aw = a0 + wv * 16;

    floatx4 acc[4];
#pragma unroll
    for (int i = 0; i < 4; ++i) acc[i] = (floatx4){0.f, 0.f, 0.f, 0.f};

#pragma unroll 4
    for (int c = 0; c < 64; ++c) {
        const int hh = c >> 3, d0 = (c & 7) * 32;
        short8 Af = *(const short8*)(z16 +
            (((size_t)b * NH + hh) * AG + aw + l15) * D + d0 + quad * 8);
#pragma unroll
        for (int et = 0; et < 4; ++et) {
            short8 Bf = *(const short8*)(WVt +
                ((size_t)hh * D + e0 + et * 16 + l15) * D + d0 + quad * 8);
            acc[et] = MFMA_BF(Af, Bf, acc[et]);
        }
    }
#pragma unroll
    for (int et = 0; et < 4; ++et)
#pragma unroll
        for (int r = 0; r < 4; ++r)
            out[((size_t)b * AG + aw + quad * 4 + r) * D + e0 + et * 16 + l15] =
                acc[et][r] * 0.125f;
}

// ---------------------------------------------------------------------------
extern "C" void kernel_launch(void* const* d_in, const int* in_sizes, int n_in,
                              void* d_out, int out_size, void* d_ws, size_t ws_size,
                              hipStream_t stream)
{
    (void)in_sizes; (void)n_in; (void)out_size; (void)ws_size;
    const float* x     = (const float*)d_in[0];
    const float* m     = (const float*)d_in[1];
    const float* W_enc = (const float*)d_in[2];
    const float* b_enc = (const float*)d_in[3];
    const float* WQ    = (const float*)d_in[4];
    const float* WK    = (const float*)d_in[5];
    const float* WV    = (const float*)d_in[6];
    float* out = (float*)d_out;
    char* ws = (char*)d_ws;

    ushort*   h_hi  = (ushort*)(ws + HHI_OFF);
    ushort*   h_lo  = (ushort*)(ws + HLO_OFF);
    ushort*   hT    = (ushort*)(ws + HT_OFF);
    ushort*   Mt_hi = (ushort*)(ws + MTHI_OFF);
    ushort*   Mt_lo = (ushort*)(ws + MTLO_OFF);
    unsigned* mbits = (unsigned*)(ws + MB_OFF);
    ushort*   WVt   = (ushort*)(ws + WVT_OFF);
    ushort*   z16   = (ushort*)(ws + Z16_OFF);

    enc_kernel<<<dim3(4, 512, 1), dim3(256), 0, stream>>>(
        x, W_enc, b_enc, h_hi, h_lo);
    prep_fused<<<dim3(3328, 1, 1), dim3(256), 0, stream>>>(
        m, mbits, h_hi, hT, WV, WVt, WQ, WK, Mt_hi, Mt_lo);
    attn_mfma<<<dim3(512, 1, 1), dim3(512), 0, stream>>>(
        h_hi, h_lo, hT, Mt_hi, Mt_lo, mbits, z16);
    out_mfma<<<dim3(4, 4, B_N), dim3(256), 0, stream>>>(z16, WVt, out);
}